// Round 4
// baseline (524.919 us; speedup 1.0000x reference)
//
#include <hip/hip_runtime.h>
#include <hip/hip_bf16.h>
#include <cstdint>

// Hgru3 fused pipeline for MI355X (gfx950).
// Workspace layout (bytes, REQUIRED total = 190,586,880 = 181.8 MiB):
//  WCAT  @0          bf16[3456][1024] (WqT|WkT|WvT|Wb1T|Wg1T|WfT-pad)
//  WB2T  @7077888    bf16[1024][128]
//  WG2T  @7340032    bf16[1024][128]
//  WOT   @7602176    bf16[1024][1024]
//  Gb    @9699328    f32[16][8192]   within-chunk cum log-decay
//  GLb   @10223616   f32[16][128]    per-chunk total log-decay
//  FP    @10231808   bf16[16384][384]  (xb1 | xg1 | fpre-pad)
//  R0    @22814720   bf16[16384][1024] (XB -> BP -> GP)
//  Qb    @56369152   bf16[16384][1024] (raw q -> reflected q -> OL)
//  Kp    @89923584   bf16[16384][1024] (silu k, token-major, for g3 intra)
//  KT    @123478016  bf16[16][128][8192] (decayed k^T -> Ob after g1)
//  VT    @157032448  bf16[16][128][8192] (v^T)
//  LTSB  lives in d_out (67,108,864 B exactly): chunk-local states, scanned
//        in place to chunk-begin states; dead before final GEMM writes d_out.

using u16 = unsigned short;
using u32 = unsigned int;
using u64 = unsigned long long;

typedef __attribute__((ext_vector_type(8))) short s16x8;
typedef __attribute__((ext_vector_type(4))) float f32x4;

__device__ __forceinline__ float b2f(u16 b){ u32 u = ((u32)b)<<16; return __builtin_bit_cast(float,u); }
__device__ __forceinline__ u16 f2b(float f){
  u32 u = __builtin_bit_cast(u32,f);
  return (u16)((u + 0x7FFFu + ((u>>16)&1u)) >> 16);   // RNE
}
__device__ __forceinline__ float sigm(float x){ return 1.f/(1.f + __expf(-x)); }
__device__ __forceinline__ float silu(float x){ return x * sigm(x); }

__device__ __forceinline__ void gload16(const void* g, void* l){
  __builtin_amdgcn_global_load_lds((const __attribute__((address_space(1))) void*)g,
                                   (__attribute__((address_space(3))) void*)l, 16, 0, 0);
}
#define MFMA(a,b,c) __builtin_amdgcn_mfma_f32_16x16x32_bf16((a),(b),(c),0,0,0)

// ---------------- diagnostic fill (ws too small; encodes ws MB) ----------------
__global__ __launch_bounds__(256) void fill_diag(float* __restrict__ p, int n, float val){
  int i = blockIdx.x*256 + threadIdx.x;
  if (i < n) p[i] = val;
}

// ---------------- cast x -> bf16 ----------------
__global__ __launch_bounds__(256) void cast_bf(const float4* __restrict__ src,
                                               ushort4* __restrict__ dst, int n4){
  int i = blockIdx.x*256 + threadIdx.x;
  int st = gridDim.x*256;
  for (; i < n4; i += st){
    float4 v = src[i];
    ushort4 o; o.x=f2b(v.x); o.y=f2b(v.y); o.z=f2b(v.z); o.w=f2b(v.w);
    dst[i] = o;
  }
}

// ---------------- weight transpose+cast: dst[n][k] = bf16(src[k][n]), zero-pad n>=Nsrc ----
__global__ __launch_bounds__(256) void wprep(const float* __restrict__ src,
                                             u16* __restrict__ dst, int K, int Nsrc){
  __shared__ float t[64][65];
  const int k0 = blockIdx.x*64, n0 = blockIdx.y*64;
  const int tid = threadIdx.x;
  #pragma unroll
  for (int e=0;e<16;e++){
    int idx = e*256 + tid;
    int r = idx>>6, c = idx&63;
    float v = 0.f;
    if (n0 + c < Nsrc) v = src[(u64)(k0+r)*Nsrc + n0 + c];
    t[r][c] = v;
  }
  __syncthreads();
  #pragma unroll
  for (int e=0;e<16;e++){
    int idx = e*256 + tid;
    int nn = idx>>6, kk = idx&63;
    dst[(u64)(n0+nn)*K + k0 + kk] = f2b(t[kk][nn]);
  }
}

// ---------------- GEMM: C[M][N] = A(bf16,[M][K] lda) @ Bt(bf16,[N][K])^T ----------------
// 128x128 tile, BK=64, 4 waves, global_load_lds + XOR-swizzled LDS.
// mode 0: C fp32 [M][N].  mode 1: C bf16 [M][N].
// mode 2: C bf16 silu token-major AND C2 = per-head transposed silu*exp(gl-g).
// mode 3: C2 = per-head transposed plain (C unused).
__global__ __launch_bounds__(256,2) void gemm_bt(const u16* __restrict__ A, int lda,
                                                 const u16* __restrict__ Bt,
                                                 void* __restrict__ C, int ldc,
                                                 int K, int mode,
                                                 u16* __restrict__ C2,
                                                 const float* __restrict__ Gp,
                                                 const float* __restrict__ GLp){
  __shared__ __align__(16) u16 As[128*64];
  __shared__ __align__(16) u16 Bs[128*64];
  const int tid = threadIdx.x, lane = tid&63, wid = tid>>6;
  const int bn0 = blockIdx.x*128, bm0 = blockIdx.y*128;
  const int wr = wid>>1, wc = wid&1;
  const int g = lane>>4, ln = lane&15;

  f32x4 acc[4][4];
  #pragma unroll
  for (int i=0;i<4;i++)
    #pragma unroll
    for (int j=0;j<4;j++) acc[i][j] = f32x4{0.f,0.f,0.f,0.f};

  const int nk = K >> 6;
  for (int kt = 0; kt < nk; ++kt){
    const int k0 = kt<<6;
    #pragma unroll
    for (int j=0;j<4;j++){
      const int p = (wid*4+j)*64 + lane;
      const int row = p>>3, sl = p&7;
      const int sc = ((sl ^ (row&7))<<3);
      gload16(A  + (u64)(bm0+row)*lda + k0 + sc, (char*)As + (wid*4+j)*1024);
      gload16(Bt + (u64)(bn0+row)*K   + k0 + sc, (char*)Bs + (wid*4+j)*1024);
    }
    __syncthreads();
    #pragma unroll
    for (int ks=0;ks<2;ks++){
      s16x8 af[4], bf[4];
      #pragma unroll
      for (int mt=0;mt<4;mt++){
        const int row = wr*64 + mt*16 + ln;
        af[mt] = *(const s16x8*)(As + row*64 + (((ks*4+g) ^ (row&7))<<3));
      }
      #pragma unroll
      for (int nt=0;nt<4;nt++){
        const int row = wc*64 + nt*16 + ln;
        bf[nt] = *(const s16x8*)(Bs + row*64 + (((ks*4+g) ^ (row&7))<<3));
      }
      #pragma unroll
      for (int mt=0;mt<4;mt++)
        #pragma unroll
        for (int nt=0;nt<4;nt++)
          acc[mt][nt] = MFMA(af[mt], bf[nt], acc[mt][nt]);
    }
    __syncthreads();
  }
  if (mode == 0){
    float* Cf = (float*)C;
    #pragma unroll
    for (int mt=0;mt<4;mt++)
      #pragma unroll
      for (int nt=0;nt<4;nt++){
        const int col = bn0 + wc*64 + nt*16 + ln;
        #pragma unroll
        for (int r=0;r<4;r++){
          const u64 row = (u64)(bm0 + wr*64 + mt*16 + g*4 + r);
          Cf[row*ldc + col] = acc[mt][nt][r];
        }
      }
  } else if (mode == 1){
    u16* Cb = (u16*)C;
    #pragma unroll
    for (int mt=0;mt<4;mt++)
      #pragma unroll
      for (int nt=0;nt<4;nt++){
        const int col = bn0 + wc*64 + nt*16 + ln;
        #pragma unroll
        for (int r=0;r<4;r++){
          const u64 row = (u64)(bm0 + wr*64 + mt*16 + g*4 + r);
          Cb[row*ldc + col] = f2b(acc[mt][nt][r]);
        }
      }
  } else {
    // transposed per-head epilogue. Tile is 128 cols = exactly one head.
    const int bh = (bm0>>13)*8 + (bn0>>7);
    const int trowb = (bm0 & 8191) + wr*64;
    float es[4][4];
    if (mode == 2){
      const float gl = GLp[bh*128 + (trowb>>6)];
      #pragma unroll
      for (int mt=0;mt<4;mt++)
        #pragma unroll
        for (int r=0;r<4;r++)
          es[mt][r] = __expf(gl - Gp[(u64)bh*8192 + trowb + mt*16 + g*4 + r]);
    }
    u16* Cb = (u16*)C;
    #pragma unroll
    for (int mt=0;mt<4;mt++){
      const int trow = trowb + mt*16 + g*4;
      #pragma unroll
      for (int nt=0;nt<4;nt++){
        const int d = wc*64 + nt*16 + ln;
        ushort4 o; u16* op = (u16*)&o;
        #pragma unroll
        for (int r=0;r<4;r++){
          float v = acc[mt][nt][r];
          if (mode == 2) v = silu(v) * es[mt][r];
          op[r] = f2b(v);
        }
        *(ushort4*)(C2 + ((u64)bh*128 + d)*8192 + trow) = o;
        if (mode == 2){
          #pragma unroll
          for (int r=0;r<4;r++)
            Cb[(u64)(bm0 + wr*64 + mt*16 + g*4 + r)*ldc + bn0 + d] = f2b(silu(acc[mt][nt][r]));
        }
      }
    }
  }
}

// ---------------- f / log-decay cumsum: one wave per (bh, chunk) ----------------
__global__ __launch_bounds__(64) void fkernel(const u16* __restrict__ FP,
                                              const float* __restrict__ llb,
                                              float* __restrict__ G, float* __restrict__ GL){
  const int c = blockIdx.x, bh = blockIdx.y;
  const int b = bh>>3, h = bh&7;
  const int t = threadIdx.x;
  const int tok = c*64 + t;
  const float fp = b2f(FP[(u64)(b*8192 + tok)*384 + 256 + h]);
  const float lb = __expf(llb[h]);
  const float f = lb + (1.f - lb) * sigm(fp);
  float x = __logf(f);
  #pragma unroll
  for (int d=1; d<64; d<<=1){
    float v = __shfl_up(x, d);
    if (t >= d) x += v;
  }
  G[(u64)bh*8192 + tok] = x;
  const float gl = __shfl(x, 63);
  if (t == 0) GL[bh*128 + c] = gl;
}

// ---------------- E1: silu(q), beta-normalize, reflect q (in place in Q) ----------------
__global__ __launch_bounds__(256) void e1_reflect(u16* __restrict__ Q,
                                                  const u16* __restrict__ BP){
  const u64 t = blockIdx.x;
  const int tid = threadIdx.x;
  __shared__ float red[8];
  u16* qrow = Q + t*1024;
  const u16* brow = BP + t*1024;
  ushort4 qv = ((const ushort4*)qrow)[tid];
  ushort4 bv = ((const ushort4*)brow)[tid];
  u16* qp = (u16*)&qv; const u16* bp = (const u16*)&bv;
  float q[4], bb[4];
  float s1 = 0.f, s2 = 0.f;
  #pragma unroll
  for (int j=0;j<4;j++){
    const float qq = silu(b2f(qp[j]));
    const float bbv = silu(b2f(bp[j]));
    q[j] = qq; bb[j] = bbv;
    s1 += bbv*bbv; s2 += qq*bbv;
  }
  #pragma unroll
  for (int d=1; d<64; d<<=1){ s1 += __shfl_xor(s1,d); s2 += __shfl_xor(s2,d); }
  const int wid = tid>>6, lane = tid&63;
  if (lane==0){ red[wid]=s1; red[4+wid]=s2; }
  __syncthreads();
  s1 = red[0]+red[1]+red[2]+red[3];
  s2 = red[4]+red[5]+red[6]+red[7];
  const float bs = 1.f/(fmaxf(sqrtf(s1), 1e-6f) * 32.f);   // /max(||b||,1e-6)/sqrt(E)
  const float coef = 2.f * s2 * bs * bs;
  #pragma unroll
  for (int j=0;j<4;j++) qp[j] = f2b(q[j] - coef*bb[j]);
  ((ushort4*)qrow)[tid] = qv;
}

// ---------------- G1: chunk-local state S^T[n][d] = sum_i v[i][n]*k'[i][d] ----------------
__global__ __launch_bounds__(256,2) void g1_local(const u16* __restrict__ KT,
                                                  const u16* __restrict__ VT,
                                                  u16* __restrict__ LT){
  __shared__ __align__(16) u16 kts[128*64];
  __shared__ __align__(16) u16 vts[128*64];
  const int c = blockIdx.x, bh = blockIdx.y;
  const int tid = threadIdx.x, lane = tid&63, wid = tid>>6;
  const int g = lane>>4, ln = lane&15;
  #pragma unroll
  for (int j=0;j<4;j++){
    const int p = (wid*4+j)*64 + lane;
    const int row = p>>3, sl = p&7;
    const int sc = ((sl ^ (row&7))<<3);
    gload16(KT + ((u64)bh*128 + row)*8192 + (u64)c*64 + sc, (char*)kts + (wid*4+j)*1024);
    gload16(VT + ((u64)bh*128 + row)*8192 + (u64)c*64 + sc, (char*)vts + (wid*4+j)*1024);
  }
  __syncthreads();
  f32x4 acc[2][8];
  #pragma unroll
  for (int mt=0;mt<2;mt++)
    #pragma unroll
    for (int dt=0;dt<8;dt++) acc[mt][dt] = f32x4{0.f,0.f,0.f,0.f};
  #pragma unroll
  for (int kk=0;kk<2;kk++){
    s16x8 av[2];
    #pragma unroll
    for (int mt=0;mt<2;mt++){
      const int row = wid*32 + mt*16 + ln;
      av[mt] = *(const s16x8*)(vts + row*64 + (((kk*4+g) ^ (row&7))<<3));
    }
    #pragma unroll
    for (int dt=0;dt<8;dt++){
      const int row = dt*16 + ln;
      const s16x8 bk = *(const s16x8*)(kts + row*64 + (((kk*4+g) ^ (row&7))<<3));
      #pragma unroll
      for (int mt=0;mt<2;mt++) acc[mt][dt] = MFMA(av[mt], bk, acc[mt][dt]);
    }
  }
  u16* out = LT + ((u64)(bh*128 + c)<<14);
  #pragma unroll
  for (int mt=0;mt<2;mt++)
    #pragma unroll
    for (int dt=0;dt<8;dt++){
      const int d = dt*16 + ln;
      #pragma unroll
      for (int r=0;r<4;r++){
        const int n = wid*32 + mt*16 + g*4 + r;
        out[n*128 + d] = f2b(acc[mt][dt][r]);
      }
    }
}

// ---------------- G2: scan over chunks IN PLACE: buf[c] becomes state BEFORE chunk c ----
__global__ __launch_bounds__(256) void g2_scan(u16* __restrict__ LS,
                                               const float* __restrict__ GL){
  __shared__ float egl[128];
  const int bh = blockIdx.y;
  if (threadIdx.x < 128) egl[threadIdx.x] = __expf(GL[bh*128 + threadIdx.x]);
  __syncthreads();
  const u64 e = (u64)blockIdx.x*256 + threadIdx.x;
  u16* P = LS + ((u64)bh<<21) + e;
  float s = 0.f;
  for (int c=0;c<128;c++){
    const float l = b2f(P[(u64)c<<14]);   // read local-state BEFORE overwrite
    P[(u64)c<<14] = f2b(s);
    s = egl[c]*s + l;
  }
}

// ---------------- G3: o = decayed-masked(q k^T) @ v + (q e^g) @ S_begin ----------------
__global__ __launch_bounds__(256,2) void g3_out(const u16* __restrict__ Qb,
                                                const u16* __restrict__ Kp,
                                                const u16* __restrict__ VT,
                                                const u16* __restrict__ SBb,
                                                const float* __restrict__ Gb,
                                                u16* __restrict__ O){
  __shared__ __align__(16) u16 qs[64*128];
  __shared__ __align__(16) u16 ks[64*128];
  __shared__ __align__(16) u16 vts[128*64];
  __shared__ __align__(16) u16 sbs[64*128];
  __shared__ __align__(16) u16 Ast[4][16*64];
  __shared__ float gg[64];
  const int c = blockIdx.x, bh = blockIdx.y;
  const int b = bh>>3, h = bh&7;
  const int tid = threadIdx.x, lane = tid&63, wid = tid>>6;
  const int g = lane>>4, ln = lane&15;
  const u64 trow0 = (u64)b*8192 + (u64)c*64;

  if (tid < 64) gg[tid] = Gb[(u64)bh*8192 + c*64 + tid];

  const u16* sbbase = SBb + ((u64)(bh*128 + c)<<14);
  #pragma unroll
  for (int j=0;j<4;j++){
    const int p = (wid*4+j)*64 + lane;
    const int row = p>>4, sl = p&15;
    const int sc = ((sl ^ (row&7))<<3);
    gload16(Qb + (trow0 + row)*1024 + h*128 + sc, (char*)qs + (wid*4+j)*1024);
    gload16(Kp + (trow0 + row)*1024 + h*128 + sc, (char*)ks + (wid*4+j)*1024);
    const int row2 = p>>3, sl2 = p&7;
    gload16(VT + ((u64)bh*128 + row2)*8192 + (u64)c*64 + ((sl2 ^ (row2&7))<<3),
            (char*)vts + (wid*4+j)*1024);
    gload16(sbbase + row*128 + sc, (char*)sbs + (wid*4+j)*1024);
  }
  __syncthreads();

  // A = q k^T  (rows i = wid*16..+16, cols j 0..63, K=d)
  f32x4 pa[4];
  #pragma unroll
  for (int jt=0;jt<4;jt++) pa[jt] = f32x4{0.f,0.f,0.f,0.f};
  #pragma unroll
  for (int kk=0;kk<4;kk++){
    const int arow = wid*16 + ln;
    const s16x8 aq = *(const s16x8*)(qs + arow*128 + (((kk*4+g) ^ (arow&7))<<3));
    #pragma unroll
    for (int jt=0;jt<4;jt++){
      const int brow = jt*16 + ln;
      const s16x8 bk = *(const s16x8*)(ks + brow*128 + (((kk*4+g) ^ (brow&7))<<3));
      pa[jt] = MFMA(aq, bk, pa[jt]);
    }
  }
  // decay+mask -> Ast (wave-private)
  #pragma unroll
  for (int jt=0;jt<4;jt++){
    const int jj = jt*16 + ln;
    const float gj = gg[jj];
    #pragma unroll
    for (int r=0;r<4;r++){
      const int il = g*4 + r;
      const int ii = wid*16 + il;
      const float v = (jj <= ii) ? pa[jt][r] * __expf(gg[ii] - gj) : 0.f;
      Ast[wid][il*64 + (((jj>>3) ^ (il&7))<<3) + (jj&7)] = f2b(v);
    }
  }
  // q' = q * exp(g_i), in place (wave-private rows; swizzle permutes within a row only)
  {
    const int row = wid*16 + (lane>>2);
    const float sc = __expf(gg[row]);
    u16* base = qs + row*128 + (lane&3)*32;
    #pragma unroll
    for (int ee=0; ee<4; ee++){
      s16x8 v = *(s16x8*)(base + ee*8);
      u16* vp = (u16*)&v;
      #pragma unroll
      for (int xj=0;xj<8;xj++) vp[xj] = f2b(b2f(vp[xj]) * sc);
      *(s16x8*)(base + ee*8) = v;
    }
  }
  f32x4 acc[8];
  #pragma unroll
  for (int i=0;i<8;i++) acc[i] = f32x4{0.f,0.f,0.f,0.f};
  // o += A @ v (K=j over 64)
  #pragma unroll
  for (int kk=0;kk<2;kk++){
    const s16x8 aa = *(const s16x8*)(Ast[wid] + ln*64 + (((kk*4+g) ^ (ln&7))<<3));
    #pragma unroll
    for (int nt=0;nt<8;nt++){
      const int brow = nt*16 + ln;
      const s16x8 bb = *(const s16x8*)(vts + brow*64 + (((kk*4+g) ^ (brow&7))<<3));
      acc[nt] = MFMA(aa, bb, acc[nt]);
    }
  }
  // o += q' @ S_begin, half 0 (n 0..63)
  #pragma unroll
  for (int kk=0;kk<4;kk++){
    const int arow = wid*16 + ln;
    const s16x8 aq = *(const s16x8*)(qs + arow*128 + (((kk*4+g) ^ (arow&7))<<3));
    #pragma unroll
    for (int nt=0;nt<4;nt++){
      const int brow = nt*16 + ln;
      const s16x8 bs = *(const s16x8*)(sbs + brow*128 + (((kk*4+g) ^ (brow&7))<<3));
      acc[nt] = MFMA(aq, bs, acc[nt]);
    }
  }
  __syncthreads();
  #pragma unroll
  for (int j=0;j<4;j++){
    const int p = (wid*4+j)*64 + lane;
    const int row = p>>4, sl = p&15;
    gload16(sbbase + 8192 + row*128 + ((sl ^ (row&7))<<3), (char*)sbs + (wid*4+j)*1024);
  }
  __syncthreads();
  // half 1 (n 64..127)
  #pragma unroll
  for (int kk=0;kk<4;kk++){
    const int arow = wid*16 + ln;
    const s16x8 aq = *(const s16x8*)(qs + arow*128 + (((kk*4+g) ^ (arow&7))<<3));
    #pragma unroll
    for (int nt=0;nt<4;nt++){
      const int brow = nt*16 + ln;
      const s16x8 bs = *(const s16x8*)(sbs + brow*128 + (((kk*4+g) ^ (brow&7))<<3));
      acc[4+nt] = MFMA(aq, bs, acc[4+nt]);
    }
  }
  u16* outp = O + trow0*1024 + h*128;
  #pragma unroll
  for (int nt=0;nt<8;nt++){
    const int n = nt*16 + ln;
    #pragma unroll
    for (int r=0;r<4;r++){
      const int i = wid*16 + g*4 + r;
      outp[(u64)i*1024 + n] = f2b(acc[nt][r]);
    }
  }
}

// ---------------- E2: gate + LayerNorm -> bf16 ----------------
__global__ __launch_bounds__(256) void e2_ln(const u16* __restrict__ O,
                                             const u16* __restrict__ GP,
                                             const float* __restrict__ lnsc,
                                             const float* __restrict__ lnbi,
                                             u16* __restrict__ OL){
  const u64 t = blockIdx.x;
  const int tid = threadIdx.x;
  __shared__ float red[8];
  ushort4 ov = ((const ushort4*)(O + t*1024))[tid];
  ushort4 gv = ((const ushort4*)(GP + t*1024))[tid];
  const u16* ovp = (const u16*)&ov;
  const u16* gvp = (const u16*)&gv;
  float o[4]; float s = 0.f, s2 = 0.f;
  #pragma unroll
  for (int j=0;j<4;j++){
    const float val = b2f(ovp[j]) * sigm(b2f(gvp[j]));
    o[j] = val; s += val; s2 += val*val;
  }
  #pragma unroll
  for (int d=1; d<64; d<<=1){ s += __shfl_xor(s,d); s2 += __shfl_xor(s2,d); }
  const int wid = tid>>6, lane = tid&63;
  if (lane==0){ red[wid]=s; red[4+wid]=s2; }
  __syncthreads();
  s = red[0]+red[1]+red[2]+red[3];
  s2 = red[4]+red[5]+red[6]+red[7];
  const float mu = s * (1.f/1024.f);
  const float var = s2 * (1.f/1024.f) - mu*mu;
  const float rs = rsqrtf(var + 1e-5f);
  ushort4 out; u16* op = (u16*)&out;
  #pragma unroll
  for (int j=0;j<4;j++){
    const int e = tid*4 + j;
    op[j] = f2b((o[j]-mu)*rs*lnsc[e] + lnbi[e]);
  }
  ((ushort4*)(OL + t*1024))[tid] = out;
}

extern "C" void kernel_launch(void* const* d_in, const int* in_sizes, int n_in,
                              void* d_out, int out_size, void* d_ws, size_t ws_size,
                              hipStream_t stream){
  const float* x   = (const float*)d_in[0];
  const float* llb = (const float*)d_in[1];
  const float* Wq  = (const float*)d_in[2];
  const float* Wk  = (const float*)d_in[3];
  const float* Wv  = (const float*)d_in[4];
  const float* Wf  = (const float*)d_in[5];
  const float* Wb1 = (const float*)d_in[6];
  const float* Wb2 = (const float*)d_in[7];
  const float* Wg1 = (const float*)d_in[8];
  const float* Wg2 = (const float*)d_in[9];
  const float* Wo  = (const float*)d_in[10];
  const float* lnsc= (const float*)d_in[11];
  const float* lnbi= (const float*)d_in[12];

  const u64 REQUIRED = 190586880ull;
  if (ws_size < REQUIRED){
    // diagnostic: encode ws MB into sentinel -> absmax ~ 1e6 + MB*1024
    const float val = 1.0e6f + (float)(u64)(ws_size>>20) * 1024.0f;
    fill_diag<<<dim3((out_size+255)/256),256,0,stream>>>((float*)d_out, out_size, val);
    return;
  }

  char* ws = (char*)d_ws;
  u16*  WCAT = (u16*)(ws + 0ull);
  u16*  WB2T = (u16*)(ws + 7077888ull);
  u16*  WG2T = (u16*)(ws + 7340032ull);
  u16*  WOT  = (u16*)(ws + 7602176ull);
  float* Gb  = (float*)(ws + 9699328ull);
  float* GLb = (float*)(ws + 10223616ull);
  u16*  FP   = (u16*)(ws + 10231808ull);
  u16*  R0   = (u16*)(ws + 22814720ull);   // XB -> BP -> GP
  u16*  Qb   = (u16*)(ws + 56369152ull);   // -> OL
  u16*  Kp   = (u16*)(ws + 89923584ull);
  u16*  KT   = (u16*)(ws + 123478016ull);  // -> Ob
  u16*  VT   = (u16*)(ws + 157032448ull);
  u16*  LTSB = (u16*)d_out;                // 67,108,864 B exactly; dead before final GEMM
  u16*  XB = R0, *BP = R0, *GP = R0;
  u16*  Ob = KT, *OL = Qb;

  cast_bf<<<dim3(4096),256,0,stream>>>((const float4*)x, (ushort4*)XB, 16384*1024/4);

  wprep<<<dim3(16,16),256,0,stream>>>(Wq,  WCAT +    0*1024, 1024, 1024);
  wprep<<<dim3(16,16),256,0,stream>>>(Wk,  WCAT + 1024*1024, 1024, 1024);
  wprep<<<dim3(16,16),256,0,stream>>>(Wv,  WCAT + 2048*1024, 1024, 1024);
  wprep<<<dim3(16, 2),256,0,stream>>>(Wb1, WCAT + 3072*1024, 1024, 128);
  wprep<<<dim3(16, 2),256,0,stream>>>(Wg1, WCAT + 3200*1024, 1024, 128);
  wprep<<<dim3(16, 2),256,0,stream>>>(Wf,  WCAT + 3328*1024, 1024, 8);
  wprep<<<dim3(2,16),256,0,stream>>>(Wb2, WB2T, 128, 1024);
  wprep<<<dim3(2,16),256,0,stream>>>(Wg2, WG2T, 128, 1024);
  wprep<<<dim3(16,16),256,0,stream>>>(Wo,  WOT, 1024, 1024);

  // fpre first (fkernel feeds the K-GEMM's decay fold)
  gemm_bt<<<dim3(1,128),256,0,stream>>>(XB, 1024, WCAT + 3328*1024, FP + 256, 384, 1024, 1,
                                        nullptr, nullptr, nullptr);
  fkernel<<<dim3(128,16),64,0,stream>>>(FP, llb, Gb, GLb);

  gemm_bt<<<dim3(8,128),256,0,stream>>>(XB, 1024, WCAT +    0*1024, Qb, 1024, 1024, 1,
                                        nullptr, nullptr, nullptr);
  gemm_bt<<<dim3(8,128),256,0,stream>>>(XB, 1024, WCAT + 1024*1024, Kp, 1024, 1024, 2,
                                        KT, Gb, GLb);
  gemm_bt<<<dim3(8,128),256,0,stream>>>(XB, 1024, WCAT + 2048*1024, nullptr, 0, 1024, 3,
                                        VT, nullptr, nullptr);
  gemm_bt<<<dim3(1,128),256,0,stream>>>(XB, 1024, WCAT + 3072*1024, FP +   0, 384, 1024, 1,
                                        nullptr, nullptr, nullptr);
  gemm_bt<<<dim3(1,128),256,0,stream>>>(XB, 1024, WCAT + 3200*1024, FP + 128, 384, 1024, 1,
                                        nullptr, nullptr, nullptr);

  // XB dead -> BP into R0
  gemm_bt<<<dim3(8,128),256,0,stream>>>(FP, 384, WB2T, BP, 1024, 128, 1,
                                        nullptr, nullptr, nullptr);
  e1_reflect<<<dim3(16384),256,0,stream>>>(Qb, BP);

  // BP dead -> GP into R0
  gemm_bt<<<dim3(8,128),256,0,stream>>>(FP + 128, 384, WG2T, GP, 1024, 128, 1,
                                        nullptr, nullptr, nullptr);

  g1_local<<<dim3(128,16),256,0,stream>>>(KT, VT, LTSB);
  g2_scan<<<dim3(64,16),256,0,stream>>>(LTSB, GLb);
  g3_out<<<dim3(128,16),256,0,stream>>>(Qb, Kp, VT, LTSB, Gb, Ob);   // Ob in dead KT

  e2_ln<<<dim3(16384),256,0,stream>>>(Ob, GP, lnsc, lnbi, OL);       // OL in dead Qb

  gemm_bt<<<dim3(8,128),256,0,stream>>>(OL, 1024, WOT, d_out, 1024, 1024, 0,
                                        nullptr, nullptr, nullptr);
}

// Round 5
// 447.778 us; speedup vs baseline: 1.1723x; 1.1723x over previous
//
#include <hip/hip_runtime.h>
#include <hip/hip_bf16.h>
#include <cstdint>

// Hgru3 fused pipeline for MI355X (gfx950).  R5: merged projection GEMM +
// XCD-chunk swizzle + occupancy 4 blocks/CU.
// Workspace layout (bytes, REQUIRED total = 190,586,880 = 181.8 MiB):
//  WCAT  @0          bf16[3456][1024] (WqT|WkT|WvT|Wb1T|Wg1T|WfT-pad)
//  WB2T  @7077888    bf16[1024][128]
//  WG2T  @7340032    bf16[1024][128]
//  WOT   @7602176    bf16[1024][1024]
//  Gb    @9699328    f32[16][8192]   within-chunk cum log-decay
//  GLb   @10223616   f32[16][128]    per-chunk total log-decay
//  FP    @10231808   bf16[16384][384]  (xb1 | xg1 | fpre-pad)
//  R0    @22814720   bf16[16384][1024] (XB -> BP -> GP)
//  Qb    @56369152   bf16[16384][1024] (raw q -> reflected q -> OL)
//  Kp    @89923584   bf16[16384][1024] (silu k, token-major, for g3 intra)
//  KT    @123478016  bf16[16][128][8192] (decayed k^T -> Ob after g1)
//  VT    @157032448  bf16[16][128][8192] (v^T)
//  LTSB  lives in d_out (67,108,864 B exactly): chunk-local states, scanned
//        in place to chunk-begin states; dead before final GEMM writes d_out.

using u16 = unsigned short;
using u32 = unsigned int;
using u64 = unsigned long long;

typedef __attribute__((ext_vector_type(8))) short s16x8;
typedef __attribute__((ext_vector_type(4))) float f32x4;

__device__ __forceinline__ float b2f(u16 b){ u32 u = ((u32)b)<<16; return __builtin_bit_cast(float,u); }
__device__ __forceinline__ u16 f2b(float f){
  u32 u = __builtin_bit_cast(u32,f);
  return (u16)((u + 0x7FFFu + ((u>>16)&1u)) >> 16);   // RNE
}
__device__ __forceinline__ float sigm(float x){ return 1.f/(1.f + __expf(-x)); }
__device__ __forceinline__ float silu(float x){ return x * sigm(x); }

__device__ __forceinline__ void gload16(const void* g, void* l){
  __builtin_amdgcn_global_load_lds((const __attribute__((address_space(1))) void*)g,
                                   (__attribute__((address_space(3))) void*)l, 16, 0, 0);
}
#define MFMA(a,b,c) __builtin_amdgcn_mfma_f32_16x16x32_bf16((a),(b),(c),0,0,0)

// XCD-chunk bijective swizzle (requires nwg % 8 == 0 — true for all grids used):
// consecutive work-ids (same A-row) land on the SAME XCD -> A-tile L2 reuse.
__device__ __forceinline__ void swz_block(int& bx, int& by){
  const int gx = gridDim.x;
  const int nwg = gx * gridDim.y;
  int lin = by*gx + bx;
  const int cpx = nwg >> 3;
  lin = (lin & 7)*cpx + (lin >> 3);
  bx = lin % gx; by = lin / gx;
}

// ---------------- diagnostic fill (ws too small; encodes ws MB) ----------------
__global__ __launch_bounds__(256) void fill_diag(float* __restrict__ p, int n, float val){
  int i = blockIdx.x*256 + threadIdx.x;
  if (i < n) p[i] = val;
}

// ---------------- cast x -> bf16 ----------------
__global__ __launch_bounds__(256) void cast_bf(const float4* __restrict__ src,
                                               ushort4* __restrict__ dst, int n4){
  int i = blockIdx.x*256 + threadIdx.x;
  int st = gridDim.x*256;
  for (; i < n4; i += st){
    float4 v = src[i];
    ushort4 o; o.x=f2b(v.x); o.y=f2b(v.y); o.z=f2b(v.z); o.w=f2b(v.w);
    dst[i] = o;
  }
}

// ---------------- weight transpose+cast: dst[n][k] = bf16(src[k][n]), zero-pad n>=Nsrc ----
__global__ __launch_bounds__(256) void wprep(const float* __restrict__ src,
                                             u16* __restrict__ dst, int K, int Nsrc){
  __shared__ float t[64][65];
  const int k0 = blockIdx.x*64, n0 = blockIdx.y*64;
  const int tid = threadIdx.x;
  #pragma unroll
  for (int e=0;e<16;e++){
    int idx = e*256 + tid;
    int r = idx>>6, c = idx&63;
    float v = 0.f;
    if (n0 + c < Nsrc) v = src[(u64)(k0+r)*Nsrc + n0 + c];
    t[r][c] = v;
  }
  __syncthreads();
  #pragma unroll
  for (int e=0;e<16;e++){
    int idx = e*256 + tid;
    int nn = idx>>6, kk = idx&63;
    dst[(u64)(n0+nn)*K + k0 + kk] = f2b(t[kk][nn]);
  }
}

// ---------------- generic GEMM: C[M][N] = A @ Bt^T.  mode 0: fp32 out, 1: bf16 out ----
__global__ __launch_bounds__(256,4) void gemm_bt(const u16* __restrict__ A, int lda,
                                                 const u16* __restrict__ Bt,
                                                 void* __restrict__ C, int ldc,
                                                 int K, int mode){
  __shared__ __align__(16) u16 As[128*64];
  __shared__ __align__(16) u16 Bs[128*64];
  const int tid = threadIdx.x, lane = tid&63, wid = tid>>6;
  int bx = blockIdx.x, by = blockIdx.y;
  swz_block(bx, by);
  const int bn0 = bx*128, bm0 = by*128;
  const int wr = wid>>1, wc = wid&1;
  const int g = lane>>4, ln = lane&15;

  f32x4 acc[4][4];
  #pragma unroll
  for (int i=0;i<4;i++)
    #pragma unroll
    for (int j=0;j<4;j++) acc[i][j] = f32x4{0.f,0.f,0.f,0.f};

  const int nk = K >> 6;
  for (int kt = 0; kt < nk; ++kt){
    const int k0 = kt<<6;
    #pragma unroll
    for (int j=0;j<4;j++){
      const int p = (wid*4+j)*64 + lane;
      const int row = p>>3, sl = p&7;
      const int sc = ((sl ^ (row&7))<<3);
      gload16(A  + (u64)(bm0+row)*lda + k0 + sc, (char*)As + (wid*4+j)*1024);
      gload16(Bt + (u64)(bn0+row)*K   + k0 + sc, (char*)Bs + (wid*4+j)*1024);
    }
    __syncthreads();
    #pragma unroll
    for (int ks=0;ks<2;ks++){
      s16x8 af[4], bf[4];
      #pragma unroll
      for (int mt=0;mt<4;mt++){
        const int row = wr*64 + mt*16 + ln;
        af[mt] = *(const s16x8*)(As + row*64 + (((ks*4+g) ^ (row&7))<<3));
      }
      #pragma unroll
      for (int nt=0;nt<4;nt++){
        const int row = wc*64 + nt*16 + ln;
        bf[nt] = *(const s16x8*)(Bs + row*64 + (((ks*4+g) ^ (row&7))<<3));
      }
      #pragma unroll
      for (int mt=0;mt<4;mt++)
        #pragma unroll
        for (int nt=0;nt<4;nt++)
          acc[mt][nt] = MFMA(af[mt], bf[nt], acc[mt][nt]);
    }
    __syncthreads();
  }
  if (mode == 0){
    float* Cf = (float*)C;
    #pragma unroll
    for (int mt=0;mt<4;mt++)
      #pragma unroll
      for (int nt=0;nt<4;nt++){
        const int col = bn0 + wc*64 + nt*16 + ln;
        #pragma unroll
        for (int r=0;r<4;r++){
          const u64 row = (u64)(bm0 + wr*64 + mt*16 + g*4 + r);
          Cf[row*ldc + col] = acc[mt][nt][r];
        }
      }
  } else {
    u16* Cb = (u16*)C;
    #pragma unroll
    for (int mt=0;mt<4;mt++)
      #pragma unroll
      for (int nt=0;nt<4;nt++){
        const int col = bn0 + wc*64 + nt*16 + ln;
        #pragma unroll
        for (int r=0;r<4;r++){
          const u64 row = (u64)(bm0 + wr*64 + mt*16 + g*4 + r);
          Cb[row*ldc + col] = f2b(acc[mt][nt][r]);
        }
      }
  }
}

// ---------------- merged projection GEMM: N = 3328 = q(8)|k(8)|v(8)|xb1(1)|xg1(1) blocks ----
// column-block cb = bn0/128 selects the fused epilogue:
//  cb 0..7  : raw q  -> Qb [tok][1024]
//  cb 8..15 : k      -> Kp[tok][1024]=silu(k)  AND  KT[bh][d][tok]=silu(k)*exp(gl-g)
//  cb 16..23: v      -> VT[bh][d][tok]
//  cb 24    : xb1    -> FP[tok][0..127]
//  cb 25    : xg1    -> FP[tok][128..255]
__global__ __launch_bounds__(256,4) void gemm_proj(const u16* __restrict__ A,
                                                   const u16* __restrict__ Bt,
                                                   u16* __restrict__ Qb,
                                                   u16* __restrict__ Kp,
                                                   u16* __restrict__ KT,
                                                   u16* __restrict__ VT,
                                                   u16* __restrict__ FP,
                                                   const float* __restrict__ Gp,
                                                   const float* __restrict__ GLp){
  __shared__ __align__(16) u16 As[128*64];
  __shared__ __align__(16) u16 Bs[128*64];
  const int tid = threadIdx.x, lane = tid&63, wid = tid>>6;
  int bx = blockIdx.x, by = blockIdx.y;
  swz_block(bx, by);
  const int bn0 = bx*128, bm0 = by*128;
  const int wr = wid>>1, wc = wid&1;
  const int g = lane>>4, ln = lane&15;

  f32x4 acc[4][4];
  #pragma unroll
  for (int i=0;i<4;i++)
    #pragma unroll
    for (int j=0;j<4;j++) acc[i][j] = f32x4{0.f,0.f,0.f,0.f};

  for (int kt = 0; kt < 16; ++kt){
    const int k0 = kt<<6;
    #pragma unroll
    for (int j=0;j<4;j++){
      const int p = (wid*4+j)*64 + lane;
      const int row = p>>3, sl = p&7;
      const int sc = ((sl ^ (row&7))<<3);
      gload16(A  + (u64)(bm0+row)*1024 + k0 + sc, (char*)As + (wid*4+j)*1024);
      gload16(Bt + (u64)(bn0+row)*1024 + k0 + sc, (char*)Bs + (wid*4+j)*1024);
    }
    __syncthreads();
    #pragma unroll
    for (int ks=0;ks<2;ks++){
      s16x8 af[4], bf[4];
      #pragma unroll
      for (int mt=0;mt<4;mt++){
        const int row = wr*64 + mt*16 + ln;
        af[mt] = *(const s16x8*)(As + row*64 + (((ks*4+g) ^ (row&7))<<3));
      }
      #pragma unroll
      for (int nt=0;nt<4;nt++){
        const int row = wc*64 + nt*16 + ln;
        bf[nt] = *(const s16x8*)(Bs + row*64 + (((ks*4+g) ^ (row&7))<<3));
      }
      #pragma unroll
      for (int mt=0;mt<4;mt++)
        #pragma unroll
        for (int nt=0;nt<4;nt++)
          acc[mt][nt] = MFMA(af[mt], bf[nt], acc[mt][nt]);
    }
    __syncthreads();
  }

  const int cb = bn0 >> 7;
  if (cb < 8){                       // ---- raw q, token-major
    #pragma unroll
    for (int mt=0;mt<4;mt++)
      #pragma unroll
      for (int nt=0;nt<4;nt++){
        const int col = bn0 + wc*64 + nt*16 + ln;
        #pragma unroll
        for (int r=0;r<4;r++)
          Qb[(u64)(bm0 + wr*64 + mt*16 + g*4 + r)*1024 + col] = f2b(acc[mt][nt][r]);
      }
  } else if (cb < 16){               // ---- k: silu token-major + decayed transposed
    const int h = cb - 8;
    const int bh = (bm0>>13)*8 + h;
    const int trowb = (bm0 & 8191) + wr*64;
    const float gl = GLp[bh*128 + (trowb>>6)];
    float es[4][4];
    #pragma unroll
    for (int mt=0;mt<4;mt++)
      #pragma unroll
      for (int r=0;r<4;r++)
        es[mt][r] = __expf(gl - Gp[(u64)bh*8192 + trowb + mt*16 + g*4 + r]);
    #pragma unroll
    for (int mt=0;mt<4;mt++){
      const int trow = trowb + mt*16 + g*4;
      #pragma unroll
      for (int nt=0;nt<4;nt++){
        const int d = wc*64 + nt*16 + ln;
        ushort4 o; u16* op = (u16*)&o;
        #pragma unroll
        for (int r=0;r<4;r++){
          const float s = silu(acc[mt][nt][r]);
          op[r] = f2b(s * es[mt][r]);
          Kp[(u64)(bm0 + wr*64 + mt*16 + g*4 + r)*1024 + h*128 + d] = f2b(s);
        }
        *(ushort4*)(KT + ((u64)bh*128 + d)*8192 + trow) = o;
      }
    }
  } else if (cb < 24){               // ---- v: transposed
    const int h = cb - 16;
    const int bh = (bm0>>13)*8 + h;
    const int trowb = (bm0 & 8191) + wr*64;
    #pragma unroll
    for (int mt=0;mt<4;mt++){
      const int trow = trowb + mt*16 + g*4;
      #pragma unroll
      for (int nt=0;nt<4;nt++){
        const int d = wc*64 + nt*16 + ln;
        ushort4 o; u16* op = (u16*)&o;
        #pragma unroll
        for (int r=0;r<4;r++) op[r] = f2b(acc[mt][nt][r]);
        *(ushort4*)(VT + ((u64)bh*128 + d)*8192 + trow) = o;
      }
    }
  } else {                           // ---- xb1 / xg1 -> FP (ldc 384)
    const int off = (cb == 24) ? 0 : 128;
    #pragma unroll
    for (int mt=0;mt<4;mt++)
      #pragma unroll
      for (int nt=0;nt<4;nt++){
        const int col = off + wc*64 + nt*16 + ln;
        #pragma unroll
        for (int r=0;r<4;r++)
          FP[(u64)(bm0 + wr*64 + mt*16 + g*4 + r)*384 + col] = f2b(acc[mt][nt][r]);
      }
  }
}

// ---------------- f / log-decay cumsum: one wave per (bh, chunk) ----------------
__global__ __launch_bounds__(64) void fkernel(const u16* __restrict__ FP,
                                              const float* __restrict__ llb,
                                              float* __restrict__ G, float* __restrict__ GL){
  const int c = blockIdx.x, bh = blockIdx.y;
  const int b = bh>>3, h = bh&7;
  const int t = threadIdx.x;
  const int tok = c*64 + t;
  const float fp = b2f(FP[(u64)(b*8192 + tok)*384 + 256 + h]);
  const float lb = __expf(llb[h]);
  const float f = lb + (1.f - lb) * sigm(fp);
  float x = __logf(f);
  #pragma unroll
  for (int d=1; d<64; d<<=1){
    float v = __shfl_up(x, d);
    if (t >= d) x += v;
  }
  G[(u64)bh*8192 + tok] = x;
  const float gl = __shfl(x, 63);
  if (t == 0) GL[bh*128 + c] = gl;
}

// ---------------- E1: silu(q), beta-normalize, reflect q (in place in Q) ----------------
__global__ __launch_bounds__(256) void e1_reflect(u16* __restrict__ Q,
                                                  const u16* __restrict__ BP){
  const u64 t = blockIdx.x;
  const int tid = threadIdx.x;
  __shared__ float red[8];
  u16* qrow = Q + t*1024;
  const u16* brow = BP + t*1024;
  ushort4 qv = ((const ushort4*)qrow)[tid];
  ushort4 bv = ((const ushort4*)brow)[tid];
  u16* qp = (u16*)&qv; const u16* bp = (const u16*)&bv;
  float q[4], bb[4];
  float s1 = 0.f, s2 = 0.f;
  #pragma unroll
  for (int j=0;j<4;j++){
    const float qq = silu(b2f(qp[j]));
    const float bbv = silu(b2f(bp[j]));
    q[j] = qq; bb[j] = bbv;
    s1 += bbv*bbv; s2 += qq*bbv;
  }
  #pragma unroll
  for (int d=1; d<64; d<<=1){ s1 += __shfl_xor(s1,d); s2 += __shfl_xor(s2,d); }
  const int wid = tid>>6, lane = tid&63;
  if (lane==0){ red[wid]=s1; red[4+wid]=s2; }
  __syncthreads();
  s1 = red[0]+red[1]+red[2]+red[3];
  s2 = red[4]+red[5]+red[6]+red[7];
  const float bs = 1.f/(fmaxf(sqrtf(s1), 1e-6f) * 32.f);   // /max(||b||,1e-6)/sqrt(E)
  const float coef = 2.f * s2 * bs * bs;
  #pragma unroll
  for (int j=0;j<4;j++) qp[j] = f2b(q[j] - coef*bb[j]);
  ((ushort4*)qrow)[tid] = qv;
}

// ---------------- G1: chunk-local state S^T[n][d] = sum_i v[i][n]*k'[i][d] ----------------
__global__ __launch_bounds__(256,4) void g1_local(const u16* __restrict__ KT,
                                                  const u16* __restrict__ VT,
                                                  u16* __restrict__ LT){
  __shared__ __align__(16) u16 kts[128*64];
  __shared__ __align__(16) u16 vts[128*64];
  const int c = blockIdx.x, bh = blockIdx.y;
  const int tid = threadIdx.x, lane = tid&63, wid = tid>>6;
  const int g = lane>>4, ln = lane&15;
  #pragma unroll
  for (int j=0;j<4;j++){
    const int p = (wid*4+j)*64 + lane;
    const int row = p>>3, sl = p&7;
    const int sc = ((sl ^ (row&7))<<3);
    gload16(KT + ((u64)bh*128 + row)*8192 + (u64)c*64 + sc, (char*)kts + (wid*4+j)*1024);
    gload16(VT + ((u64)bh*128 + row)*8192 + (u64)c*64 + sc, (char*)vts + (wid*4+j)*1024);
  }
  __syncthreads();
  f32x4 acc[2][8];
  #pragma unroll
  for (int mt=0;mt<2;mt++)
    #pragma unroll
    for (int dt=0;dt<8;dt++) acc[mt][dt] = f32x4{0.f,0.f,0.f,0.f};
  #pragma unroll
  for (int kk=0;kk<2;kk++){
    s16x8 av[2];
    #pragma unroll
    for (int mt=0;mt<2;mt++){
      const int row = wid*32 + mt*16 + ln;
      av[mt] = *(const s16x8*)(vts + row*64 + (((kk*4+g) ^ (row&7))<<3));
    }
    #pragma unroll
    for (int dt=0;dt<8;dt++){
      const int row = dt*16 + ln;
      const s16x8 bk = *(const s16x8*)(kts + row*64 + (((kk*4+g) ^ (row&7))<<3));
      #pragma unroll
      for (int mt=0;mt<2;mt++) acc[mt][dt] = MFMA(av[mt], bk, acc[mt][dt]);
    }
  }
  u16* out = LT + ((u64)(bh*128 + c)<<14);
  #pragma unroll
  for (int mt=0;mt<2;mt++)
    #pragma unroll
    for (int dt=0;dt<8;dt++){
      const int d = dt*16 + ln;
      #pragma unroll
      for (int r=0;r<4;r++){
        const int n = wid*32 + mt*16 + g*4 + r;
        out[n*128 + d] = f2b(acc[mt][dt][r]);
      }
    }
}

// ---------------- G2: scan over chunks IN PLACE: buf[c] becomes state BEFORE chunk c ----
__global__ __launch_bounds__(256) void g2_scan(u16* __restrict__ LS,
                                               const float* __restrict__ GL){
  __shared__ float egl[128];
  const int bh = blockIdx.y;
  if (threadIdx.x < 128) egl[threadIdx.x] = __expf(GL[bh*128 + threadIdx.x]);
  __syncthreads();
  const u64 e = (u64)blockIdx.x*256 + threadIdx.x;
  u16* P = LS + ((u64)bh<<21) + e;
  float s = 0.f;
  for (int c=0;c<128;c++){
    const float l = b2f(P[(u64)c<<14]);   // read local-state BEFORE overwrite
    P[(u64)c<<14] = f2b(s);
    s = egl[c]*s + l;
  }
}

// ---------------- G3: o = decayed-masked(q k^T) @ v + (q e^g) @ S_begin ----------------
__global__ __launch_bounds__(256,2) void g3_out(const u16* __restrict__ Qb,
                                                const u16* __restrict__ Kp,
                                                const u16* __restrict__ VT,
                                                const u16* __restrict__ SBb,
                                                const float* __restrict__ Gb,
                                                u16* __restrict__ O){
  __shared__ __align__(16) u16 qs[64*128];
  __shared__ __align__(16) u16 ks[64*128];
  __shared__ __align__(16) u16 vts[128*64];
  __shared__ __align__(16) u16 sbs[64*128];
  __shared__ __align__(16) u16 Ast[4][16*64];
  __shared__ float gg[64];
  const int c = blockIdx.x, bh = blockIdx.y;
  const int b = bh>>3, h = bh&7;
  const int tid = threadIdx.x, lane = tid&63, wid = tid>>6;
  const int g = lane>>4, ln = lane&15;
  const u64 trow0 = (u64)b*8192 + (u64)c*64;

  if (tid < 64) gg[tid] = Gb[(u64)bh*8192 + c*64 + tid];

  const u16* sbbase = SBb + ((u64)(bh*128 + c)<<14);
  #pragma unroll
  for (int j=0;j<4;j++){
    const int p = (wid*4+j)*64 + lane;
    const int row = p>>4, sl = p&15;
    const int sc = ((sl ^ (row&7))<<3);
    gload16(Qb + (trow0 + row)*1024 + h*128 + sc, (char*)qs + (wid*4+j)*1024);
    gload16(Kp + (trow0 + row)*1024 + h*128 + sc, (char*)ks + (wid*4+j)*1024);
    const int row2 = p>>3, sl2 = p&7;
    gload16(VT + ((u64)bh*128 + row2)*8192 + (u64)c*64 + ((sl2 ^ (row2&7))<<3),
            (char*)vts + (wid*4+j)*1024);
    gload16(sbbase + row*128 + sc, (char*)sbs + (wid*4+j)*1024);
  }
  __syncthreads();

  // A = q k^T  (rows i = wid*16..+16, cols j 0..63, K=d)
  f32x4 pa[4];
  #pragma unroll
  for (int jt=0;jt<4;jt++) pa[jt] = f32x4{0.f,0.f,0.f,0.f};
  #pragma unroll
  for (int kk=0;kk<4;kk++){
    const int arow = wid*16 + ln;
    const s16x8 aq = *(const s16x8*)(qs + arow*128 + (((kk*4+g) ^ (arow&7))<<3));
    #pragma unroll
    for (int jt=0;jt<4;jt++){
      const int brow = jt*16 + ln;
      const s16x8 bk = *(const s16x8*)(ks + brow*128 + (((kk*4+g) ^ (brow&7))<<3));
      pa[jt] = MFMA(aq, bk, pa[jt]);
    }
  }
  // decay+mask -> Ast (wave-private)
  #pragma unroll
  for (int jt=0;jt<4;jt++){
    const int jj = jt*16 + ln;
    const float gj = gg[jj];
    #pragma unroll
    for (int r=0;r<4;r++){
      const int il = g*4 + r;
      const int ii = wid*16 + il;
      const float v = (jj <= ii) ? pa[jt][r] * __expf(gg[ii] - gj) : 0.f;
      Ast[wid][il*64 + (((jj>>3) ^ (il&7))<<3) + (jj&7)] = f2b(v);
    }
  }
  // q' = q * exp(g_i), in place (wave-private rows; swizzle permutes within a row only)
  {
    const int row = wid*16 + (lane>>2);
    const float sc = __expf(gg[row]);
    u16* base = qs + row*128 + (lane&3)*32;
    #pragma unroll
    for (int ee=0; ee<4; ee++){
      s16x8 v = *(s16x8*)(base + ee*8);
      u16* vp = (u16*)&v;
      #pragma unroll
      for (int xj=0;xj<8;xj++) vp[xj] = f2b(b2f(vp[xj]) * sc);
      *(s16x8*)(base + ee*8) = v;
    }
  }
  f32x4 acc[8];
  #pragma unroll
  for (int i=0;i<8;i++) acc[i] = f32x4{0.f,0.f,0.f,0.f};
  // o += A @ v (K=j over 64)
  #pragma unroll
  for (int kk=0;kk<2;kk++){
    const s16x8 aa = *(const s16x8*)(Ast[wid] + ln*64 + (((kk*4+g) ^ (ln&7))<<3));
    #pragma unroll
    for (int nt=0;nt<8;nt++){
      const int brow = nt*16 + ln;
      const s16x8 bb = *(const s16x8*)(vts + brow*64 + (((kk*4+g) ^ (brow&7))<<3));
      acc[nt] = MFMA(aa, bb, acc[nt]);
    }
  }
  // o += q' @ S_begin, half 0 (n 0..63)
  #pragma unroll
  for (int kk=0;kk<4;kk++){
    const int arow = wid*16 + ln;
    const s16x8 aq = *(const s16x8*)(qs + arow*128 + (((kk*4+g) ^ (arow&7))<<3));
    #pragma unroll
    for (int nt=0;nt<4;nt++){
      const int brow = nt*16 + ln;
      const s16x8 bs = *(const s16x8*)(sbs + brow*128 + (((kk*4+g) ^ (brow&7))<<3));
      acc[nt] = MFMA(aq, bs, acc[nt]);
    }
  }
  __syncthreads();
  #pragma unroll
  for (int j=0;j<4;j++){
    const int p = (wid*4+j)*64 + lane;
    const int row = p>>4, sl = p&15;
    gload16(sbbase + 8192 + row*128 + ((sl ^ (row&7))<<3), (char*)sbs + (wid*4+j)*1024);
  }
  __syncthreads();
  // half 1 (n 64..127)
  #pragma unroll
  for (int kk=0;kk<4;kk++){
    const int arow = wid*16 + ln;
    const s16x8 aq = *(const s16x8*)(qs + arow*128 + (((kk*4+g) ^ (arow&7))<<3));
    #pragma unroll
    for (int nt=0;nt<4;nt++){
      const int brow = nt*16 + ln;
      const s16x8 bs = *(const s16x8*)(sbs + brow*128 + (((kk*4+g) ^ (brow&7))<<3));
      acc[4+nt] = MFMA(aq, bs, acc[4+nt]);
    }
  }
  u16* outp = O + trow0*1024 + h*128;
  #pragma unroll
  for (int nt=0;nt<8;nt++){
    const int n = nt*16 + ln;
    #pragma unroll
    for (int r=0;r<4;r++){
      const int i = wid*16 + g*4 + r;
      outp[(u64)i*1024 + n] = f2b(acc[nt][r]);
    }
  }
}

// ---------------- E2: gate + LayerNorm -> bf16 ----------------
__global__ __launch_bounds__(256) void e2_ln(const u16* __restrict__ O,
                                             const u16* __restrict__ GP,
                                             const float* __restrict__ lnsc,
                                             const float* __restrict__ lnbi,
                                             u16* __restrict__ OL){
  const u64 t = blockIdx.x;
  const int tid = threadIdx.x;
  __shared__ float red[8];
  ushort4 ov = ((const ushort4*)(O + t*1024))[tid];
  ushort4 gv = ((const ushort4*)(GP + t*1024))[tid];
  const u16* ovp = (const u16*)&ov;
  const u16* gvp = (const u16*)&gv;
  float o[4]; float s = 0.f, s2 = 0.f;
  #pragma unroll
  for (int j=0;j<4;j++){
    const float val = b2f(ovp[j]) * sigm(b2f(gvp[j]));
    o[j] = val; s += val; s2 += val*val;
  }
  #pragma unroll
  for (int d=1; d<64; d<<=1){ s += __shfl_xor(s,d); s2 += __shfl_xor(s2,d); }
  const int wid = tid>>6, lane = tid&63;
  if (lane==0){ red[wid]=s; red[4+wid]=s2; }
  __syncthreads();
  s = red[0]+red[1]+red[2]+red[3];
  s2 = red[4]+red[5]+red[6]+red[7];
  const float mu = s * (1.f/1024.f);
  const float var = s2 * (1.f/1024.f) - mu*mu;
  const float rs = rsqrtf(var + 1e-5f);
  ushort4 out; u16* op = (u16*)&out;
  #pragma unroll
  for (int j=0;j<4;j++){
    const int e = tid*4 + j;
    op[j] = f2b((o[j]-mu)*rs*lnsc[e] + lnbi[e]);
  }
  ((ushort4*)(OL + t*1024))[tid] = out;
}

extern "C" void kernel_launch(void* const* d_in, const int* in_sizes, int n_in,
                              void* d_out, int out_size, void* d_ws, size_t ws_size,
                              hipStream_t stream){
  const float* x   = (const float*)d_in[0];
  const float* llb = (const float*)d_in[1];
  const float* Wq  = (const float*)d_in[2];
  const float* Wk  = (const float*)d_in[3];
  const float* Wv  = (const float*)d_in[4];
  const float* Wf  = (const float*)d_in[5];
  const float* Wb1 = (const float*)d_in[6];
  const float* Wb2 = (const float*)d_in[7];
  const float* Wg1 = (const float*)d_in[8];
  const float* Wg2 = (const float*)d_in[9];
  const float* Wo  = (const float*)d_in[10];
  const float* lnsc= (const float*)d_in[11];
  const float* lnbi= (const float*)d_in[12];

  const u64 REQUIRED = 190586880ull;
  if (ws_size < REQUIRED){
    const float val = 1.0e6f + (float)(u64)(ws_size>>20) * 1024.0f;
    fill_diag<<<dim3((out_size+255)/256),256,0,stream>>>((float*)d_out, out_size, val);
    return;
  }

  char* ws = (char*)d_ws;
  u16*  WCAT = (u16*)(ws + 0ull);
  u16*  WB2T = (u16*)(ws + 7077888ull);
  u16*  WG2T = (u16*)(ws + 7340032ull);
  u16*  WOT  = (u16*)(ws + 7602176ull);
  float* Gb  = (float*)(ws + 9699328ull);
  float* GLb = (float*)(ws + 10223616ull);
  u16*  FP   = (u16*)(ws + 10231808ull);
  u16*  R0   = (u16*)(ws + 22814720ull);   // XB -> BP -> GP
  u16*  Qb   = (u16*)(ws + 56369152ull);   // -> OL
  u16*  Kp   = (u16*)(ws + 89923584ull);
  u16*  KT   = (u16*)(ws + 123478016ull);  // -> Ob
  u16*  VT   = (u16*)(ws + 157032448ull);
  u16*  LTSB = (u16*)d_out;                // 67,108,864 B exactly; dead before final GEMM
  u16*  XB = R0, *BP = R0, *GP = R0;
  u16*  Ob = KT, *OL = Qb;

  cast_bf<<<dim3(4096),256,0,stream>>>((const float4*)x, (ushort4*)XB, 16384*1024/4);

  wprep<<<dim3(16,16),256,0,stream>>>(Wq,  WCAT +    0*1024, 1024, 1024);
  wprep<<<dim3(16,16),256,0,stream>>>(Wk,  WCAT + 1024*1024, 1024, 1024);
  wprep<<<dim3(16,16),256,0,stream>>>(Wv,  WCAT + 2048*1024, 1024, 1024);
  wprep<<<dim3(16, 2),256,0,stream>>>(Wb1, WCAT + 3072*1024, 1024, 128);
  wprep<<<dim3(16, 2),256,0,stream>>>(Wg1, WCAT + 3200*1024, 1024, 128);
  wprep<<<dim3(16, 2),256,0,stream>>>(Wf,  WCAT + 3328*1024, 1024, 8);
  wprep<<<dim3(2,16),256,0,stream>>>(Wb2, WB2T, 128, 1024);
  wprep<<<dim3(2,16),256,0,stream>>>(Wg2, WG2T, 128, 1024);
  wprep<<<dim3(16,16),256,0,stream>>>(Wo,  WOT, 1024, 1024);

  // fpre first (fkernel feeds the merged GEMM's K decay fold)
  gemm_bt<<<dim3(1,128),256,0,stream>>>(XB, 1024, WCAT + 3328*1024, FP + 256, 384, 1024, 1);
  fkernel<<<dim3(128,16),64,0,stream>>>(FP, llb, Gb, GLb);

  // merged q|k|v|xb1|xg1 projection (A read once)
  gemm_proj<<<dim3(26,128),256,0,stream>>>(XB, WCAT, Qb, Kp, KT, VT, FP, Gb, GLb);

  // XB dead -> BP into R0
  gemm_bt<<<dim3(8,128),256,0,stream>>>(FP, 384, WB2T, BP, 1024, 128, 1);
  e1_reflect<<<dim3(16384),256,0,stream>>>(Qb, BP);

  // BP dead -> GP into R0
  gemm_bt<<<dim3(8,128),256,0,stream>>>(FP + 128, 384, WG2T, GP, 1024, 128, 1);

  g1_local<<<dim3(128,16),256,0,stream>>>(KT, VT, LTSB);
  g2_scan<<<dim3(64,16),256,0,stream>>>(LTSB, GLb);
  g3_out<<<dim3(128,16),256,0,stream>>>(Qb, Kp, VT, LTSB, Gb, Ob);   // Ob in dead KT

  e2_ln<<<dim3(16384),256,0,stream>>>(Ob, GP, lnsc, lnbi, OL);       // OL in dead Qb

  gemm_bt<<<dim3(8,128),256,0,stream>>>(OL, 1024, WOT, d_out, 1024, 1024, 0);
}

// Round 7
// 377.884 us; speedup vs baseline: 1.3891x; 1.1850x over previous
//
#include <hip/hip_runtime.h>
#include <hip/hip_bf16.h>
#include <cstdint>

// Hgru3 fused pipeline for MI355X (gfx950).  R6: 256x256 double-buffered
// counted-vmcnt GEMM (T3/T4) for proj/BP/GP/o + merged wprep.
// Workspace layout unchanged (REQUIRED 190,586,880 B):
//  WCAT@0 WB2T@7077888 WG2T@7340032 WOT@7602176 Gb@9699328 GLb@10223616
//  FP@10231808 R0@22814720(XB->BP->GP) Qb@56369152(->OL) Kp@89923584
//  KT@123478016(->Ob) VT@157032448 ; LTSB lives in d_out.

using u16 = unsigned short;
using u32 = unsigned int;
using u64 = unsigned long long;

typedef __attribute__((ext_vector_type(8))) short s16x8;
typedef __attribute__((ext_vector_type(4))) float f32x4;

__device__ __forceinline__ float b2f(u16 b){ u32 u = ((u32)b)<<16; return __builtin_bit_cast(float,u); }
__device__ __forceinline__ u16 f2b(float f){
  u32 u = __builtin_bit_cast(u32,f);
  return (u16)((u + 0x7FFFu + ((u>>16)&1u)) >> 16);   // RNE
}
__device__ __forceinline__ float sigm(float x){ return 1.f/(1.f + __expf(-x)); }
__device__ __forceinline__ float silu(float x){ return x * sigm(x); }

__device__ __forceinline__ void gload16(const void* g, void* l){
  __builtin_amdgcn_global_load_lds((const __attribute__((address_space(1))) void*)g,
                                   (__attribute__((address_space(3))) void*)l, 16, 0, 0);
}
#define MFMA(a,b,c) __builtin_amdgcn_mfma_f32_16x16x32_bf16((a),(b),(c),0,0,0)

__device__ __forceinline__ void bar(){
  asm volatile("" ::: "memory");
  __builtin_amdgcn_s_barrier();
  asm volatile("" ::: "memory");
}
__device__ __forceinline__ void wait_vm8(){
  asm volatile("s_waitcnt vmcnt(8)" ::: "memory");
  __builtin_amdgcn_sched_barrier(0);
}
__device__ __forceinline__ void wait_vm0(){
  asm volatile("s_waitcnt vmcnt(0)" ::: "memory");
  __builtin_amdgcn_sched_barrier(0);
}

// XCD-chunk bijective swizzle (requires nwg % 8 == 0 — true for all grids used).
__device__ __forceinline__ void swz_block(int& bx, int& by){
  const int gx = gridDim.x;
  const int nwg = gx * gridDim.y;
  int lin = by*gx + bx;
  const int cpx = nwg >> 3;
  lin = (lin & 7)*cpx + (lin >> 3);
  bx = lin % gx; by = lin / gx;
}

// ---------------- diagnostic fill ----------------
__global__ __launch_bounds__(256) void fill_diag(float* __restrict__ p, int n, float val){
  int i = blockIdx.x*256 + threadIdx.x;
  if (i < n) p[i] = val;
}

// ---------------- cast x -> bf16 ----------------
__global__ __launch_bounds__(256) void cast_bf(const float4* __restrict__ src,
                                               ushort4* __restrict__ dst, int n4){
  int i = blockIdx.x*256 + threadIdx.x;
  int st = gridDim.x*256;
  for (; i < n4; i += st){
    float4 v = src[i];
    ushort4 o; o.x=f2b(v.x); o.y=f2b(v.y); o.z=f2b(v.z); o.w=f2b(v.w);
    dst[i] = o;
  }
}

// ---------------- merged weight transpose+cast (all 9 weights, z-indexed) ----------------
__global__ __launch_bounds__(256) void wprep_all(const float* __restrict__ Wq,
                                                 const float* __restrict__ Wk,
                                                 const float* __restrict__ Wv,
                                                 const float* __restrict__ Wf,
                                                 const float* __restrict__ Wb1,
                                                 const float* __restrict__ Wb2,
                                                 const float* __restrict__ Wg1,
                                                 const float* __restrict__ Wg2,
                                                 const float* __restrict__ Wo,
                                                 u16* __restrict__ WCAT,
                                                 u16* __restrict__ WB2T,
                                                 u16* __restrict__ WG2T,
                                                 u16* __restrict__ WOT){
  const int z = blockIdx.z;
  const float* src; u16* dst; int K, Nsrc, kb, nb;
  switch(z){
    case 0: src=Wq;  dst=WCAT;            K=1024; Nsrc=1024; kb=16; nb=16; break;
    case 1: src=Wk;  dst=WCAT+1024*1024;  K=1024; Nsrc=1024; kb=16; nb=16; break;
    case 2: src=Wv;  dst=WCAT+2048*1024;  K=1024; Nsrc=1024; kb=16; nb=16; break;
    case 3: src=Wb1; dst=WCAT+3072*1024;  K=1024; Nsrc=128;  kb=16; nb=2;  break;
    case 4: src=Wg1; dst=WCAT+3200*1024;  K=1024; Nsrc=128;  kb=16; nb=2;  break;
    case 5: src=Wf;  dst=WCAT+3328*1024;  K=1024; Nsrc=8;    kb=16; nb=2;  break;
    case 6: src=Wb2; dst=WB2T;            K=128;  Nsrc=1024; kb=2;  nb=16; break;
    case 7: src=Wg2; dst=WG2T;            K=128;  Nsrc=1024; kb=2;  nb=16; break;
    default:src=Wo;  dst=WOT;             K=1024; Nsrc=1024; kb=16; nb=16; break;
  }
  if (blockIdx.x >= (u32)kb || blockIdx.y >= (u32)nb) return;
  __shared__ float t[64][65];
  const int k0 = blockIdx.x*64, n0 = blockIdx.y*64;
  const int tid = threadIdx.x;
  #pragma unroll
  for (int e=0;e<16;e++){
    int idx = e*256 + tid;
    int r = idx>>6, c = idx&63;
    float v = 0.f;
    if (n0 + c < Nsrc) v = src[(u64)(k0+r)*Nsrc + n0 + c];
    t[r][c] = v;
  }
  __syncthreads();
  #pragma unroll
  for (int e=0;e<16;e++){
    int idx = e*256 + tid;
    int nn = idx>>6, kk = idx&63;
    dst[(u64)(n0+nn)*K + k0 + kk] = f2b(t[kk][nn]);
  }
}

// ---------------- 128² GEMM (kept for the small fpre projection only) ----------------
__global__ __launch_bounds__(256,4) void gemm_bt(const u16* __restrict__ A, int lda,
                                                 const u16* __restrict__ Bt,
                                                 void* __restrict__ C, int ldc,
                                                 int K, int mode){
  __shared__ __align__(16) u16 As[128*64];
  __shared__ __align__(16) u16 Bs[128*64];
  const int tid = threadIdx.x, lane = tid&63, wid = tid>>6;
  int bx = blockIdx.x, by = blockIdx.y;
  swz_block(bx, by);
  const int bn0 = bx*128, bm0 = by*128;
  const int wr = wid>>1, wc = wid&1;
  const int g = lane>>4, ln = lane&15;

  f32x4 acc[4][4];
  #pragma unroll
  for (int i=0;i<4;i++)
    #pragma unroll
    for (int j=0;j<4;j++) acc[i][j] = f32x4{0.f,0.f,0.f,0.f};

  const int nk = K >> 6;
  for (int kt = 0; kt < nk; ++kt){
    const int k0 = kt<<6;
    #pragma unroll
    for (int j=0;j<4;j++){
      const int p = (wid*4+j)*64 + lane;
      const int row = p>>3, sl = p&7;
      const int sc = ((sl ^ (row&7))<<3);
      gload16(A  + (u64)(bm0+row)*lda + k0 + sc, (char*)As + (wid*4+j)*1024);
      gload16(Bt + (u64)(bn0+row)*K   + k0 + sc, (char*)Bs + (wid*4+j)*1024);
    }
    __syncthreads();
    #pragma unroll
    for (int ks=0;ks<2;ks++){
      s16x8 af[4], bf[4];
      #pragma unroll
      for (int mt=0;mt<4;mt++){
        const int row = wr*64 + mt*16 + ln;
        af[mt] = *(const s16x8*)(As + row*64 + (((ks*4+g) ^ (row&7))<<3));
      }
      #pragma unroll
      for (int nt=0;nt<4;nt++){
        const int row = wc*64 + nt*16 + ln;
        bf[nt] = *(const s16x8*)(Bs + row*64 + (((ks*4+g) ^ (row&7))<<3));
      }
      #pragma unroll
      for (int mt=0;mt<4;mt++)
        #pragma unroll
        for (int nt=0;nt<4;nt++)
          acc[mt][nt] = MFMA(af[mt], bf[nt], acc[mt][nt]);
    }
    __syncthreads();
  }
  if (mode == 0){
    float* Cf = (float*)C;
    #pragma unroll
    for (int mt=0;mt<4;mt++)
      #pragma unroll
      for (int nt=0;nt<4;nt++){
        const int col = bn0 + wc*64 + nt*16 + ln;
        #pragma unroll
        for (int r=0;r<4;r++)
          Cf[(u64)(bm0 + wr*64 + mt*16 + g*4 + r)*ldc + col] = acc[mt][nt][r];
      }
  } else {
    u16* Cb = (u16*)C;
    #pragma unroll
    for (int mt=0;mt<4;mt++)
      #pragma unroll
      for (int nt=0;nt<4;nt++){
        const int col = bn0 + wc*64 + nt*16 + ln;
        #pragma unroll
        for (int r=0;r<4;r++)
          Cb[(u64)(bm0 + wr*64 + mt*16 + g*4 + r)*ldc + col] = f2b(acc[mt][nt][r]);
      }
  }
}

// ======== 256x256 double-buffered counted-vmcnt GEMM core (8 waves, BK=64) ========
// LDS: lds[2 bufs][A 16384 u16 | B 16384 u16] = 128 KiB.  8 gload_lds/thread/K-tile.
// Pipeline: STAGE(t+1,c^1); vmcnt(8); barrier; ds_read+MFMA from buf c; barrier.
#define STAGE256(kt_, c_)                                                              \
  do{ const int kk0 = (kt_)<<6;                                                        \
    _Pragma("unroll")                                                                  \
    for (int j=0;j<4;j++){                                                             \
      const int p = j*512 + tid;                                                       \
      const int row = p>>3, sl = p&7;                                                  \
      const int sc = ((sl ^ (row&7))<<3);                                              \
      gload16(A  + (u64)(bm0+row)*lda + kk0 + sc,                                      \
              (char*)lds + (c_)*65536 + (j*8+wid)*1024);                               \
      gload16(Bt + (u64)(bn0+row)*K   + kk0 + sc,                                      \
              (char*)lds + (c_)*65536 + 32768 + (j*8+wid)*1024);                       \
    } }while(0)

#define GEMM256_CORE()                                                                 \
  f32x4 acc[8][4];                                                                     \
  _Pragma("unroll")                                                                    \
  for (int i=0;i<8;i++)                                                                \
    _Pragma("unroll")                                                                  \
    for (int j=0;j<4;j++) acc[i][j] = f32x4{0.f,0.f,0.f,0.f};                          \
  const int nk = K >> 6;                                                               \
  STAGE256(0, 0);                                                                      \
  int cbuf = 0;                                                                        \
  for (int kt = 0; kt < nk; ++kt){                                                     \
    if (kt+1 < nk){ STAGE256(kt+1, cbuf^1); wait_vm8(); } else { wait_vm0(); }         \
    bar();                                                                             \
    const u16* As_c = lds + cbuf*32768;                                                \
    const u16* Bs_c = As_c + 16384;                                                    \
    s16x8 bfr[2][4];                                                                   \
    _Pragma("unroll")                                                                  \
    for (int ks=0;ks<2;ks++)                                                           \
      _Pragma("unroll")                                                                \
      for (int n=0;n<4;n++){                                                           \
        const int row = wc*64 + n*16 + ln;                                             \
        bfr[ks][n] = *(const s16x8*)(Bs_c + row*64 + (((ks*4+g) ^ (row&7))<<3));       \
      }                                                                                \
    _Pragma("unroll")                                                                  \
    for (int m=0;m<8;m++){                                                             \
      const int arow = wr*128 + m*16 + ln;                                             \
      _Pragma("unroll")                                                                \
      for (int ks=0;ks<2;ks++){                                                        \
        const s16x8 af = *(const s16x8*)(As_c + arow*64 + (((ks*4+g) ^ (arow&7))<<3)); \
        _Pragma("unroll")                                                              \
        for (int n=0;n<4;n++) acc[m][n] = MFMA(af, bfr[ks][n], acc[m][n]);             \
      }                                                                                \
    }                                                                                  \
    bar();                                                                             \
    cbuf ^= 1;                                                                         \
  }

// ---------------- generic 256² GEMM: mode 0 fp32 out, mode 1 bf16 out ----------------
__global__ __launch_bounds__(512,2) void gemm256(const u16* __restrict__ A, int lda,
                                                 const u16* __restrict__ Bt,
                                                 void* __restrict__ C, int ldc,
                                                 int K, int mode){
  __shared__ __align__(16) u16 lds[2*32768];
  const int tid = threadIdx.x, lane = tid&63, wid = tid>>6;
  int bx = blockIdx.x, by = blockIdx.y;
  swz_block(bx, by);
  const int bn0 = bx*256, bm0 = by*256;
  const int wr = wid>>2, wc = wid&3;
  const int g = lane>>4, ln = lane&15;
  GEMM256_CORE();
  if (mode == 0){
    float* Cf = (float*)C;
    #pragma unroll
    for (int m=0;m<8;m++)
      #pragma unroll
      for (int n=0;n<4;n++){
        const int col = bn0 + wc*64 + n*16 + ln;
        #pragma unroll
        for (int r=0;r<4;r++)
          Cf[(u64)(bm0 + wr*128 + m*16 + g*4 + r)*ldc + col] = acc[m][n][r];
      }
  } else {
    u16* Cb = (u16*)C;
    #pragma unroll
    for (int m=0;m<8;m++)
      #pragma unroll
      for (int n=0;n<4;n++){
        const int col = bn0 + wc*64 + n*16 + ln;
        #pragma unroll
        for (int r=0;r<4;r++)
          Cb[(u64)(bm0 + wr*128 + m*16 + g*4 + r)*ldc + col] = f2b(acc[m][n][r]);
      }
  }
}

// ---------------- merged projection GEMM (256² core), N = 3328 ----------------
// per-wave head-block hb = (bn0+wc*64)>>7:
//  hb 0..7  : raw q  -> Qb[tok][1024]
//  hb 8..15 : k      -> Kp[tok][1024]=silu  AND  KT[bh][d][tok]=silu*exp(gl-g)
//  hb 16..23: v      -> VT[bh][d][tok]
//  hb 24..25: xb1/xg1 -> FP[tok][col-3072]
__global__ __launch_bounds__(512,2) void gemm_proj(const u16* __restrict__ A,
                                                   const u16* __restrict__ Bt,
                                                   u16* __restrict__ Qb,
                                                   u16* __restrict__ Kp,
                                                   u16* __restrict__ KT,
                                                   u16* __restrict__ VT,
                                                   u16* __restrict__ FP,
                                                   const float* __restrict__ Gp,
                                                   const float* __restrict__ GLp){
  __shared__ __align__(16) u16 lds[2*32768];
  const int tid = threadIdx.x, lane = tid&63, wid = tid>>6;
  int bx = blockIdx.x, by = blockIdx.y;
  swz_block(bx, by);
  const int bn0 = bx*256, bm0 = by*256;
  const int lda = 1024, K = 1024;
  const int wr = wid>>2, wc = wid&3;
  const int g = lane>>4, ln = lane&15;
  GEMM256_CORE();

  const int cw0 = bn0 + wc*64;          // wave col base (multiple of 64)
  const int hb = cw0 >> 7;
  if (hb < 8){                          // ---- raw q
    #pragma unroll
    for (int m=0;m<8;m++)
      #pragma unroll
      for (int n=0;n<4;n++){
        const int col = cw0 + n*16 + ln;
        #pragma unroll
        for (int r=0;r<4;r++)
          Qb[(u64)(bm0 + wr*128 + m*16 + g*4 + r)*1024 + col] = f2b(acc[m][n][r]);
      }
  } else if (hb < 16){                  // ---- k
    const int h = hb - 8;
    const int bh = (bm0>>13)*8 + h;
    const int dbase = cw0 & 127;
    #pragma unroll
    for (int m=0;m<8;m++){
      const int trow = (bm0&8191) + wr*128 + m*16 + g*4;
      const float gl = GLp[bh*128 + (trow>>6)];
      float es[4];
      #pragma unroll
      for (int r=0;r<4;r++) es[r] = __expf(gl - Gp[(u64)bh*8192 + trow + r]);
      #pragma unroll
      for (int n=0;n<4;n++){
        const int d = dbase + n*16 + ln;
        ushort4 o; u16* op = (u16*)&o;
        #pragma unroll
        for (int r=0;r<4;r++){
          const float s = silu(acc[m][n][r]);
          op[r] = f2b(s * es[r]);
          Kp[(u64)(bm0 + wr*128 + m*16 + g*4 + r)*1024 + h*128 + d] = f2b(s);
        }
        *(ushort4*)(KT + ((u64)bh*128 + d)*8192 + trow) = o;
      }
    }
  } else if (hb < 24){                  // ---- v transposed
    const int h = hb - 16;
    const int bh = (bm0>>13)*8 + h;
    const int dbase = cw0 & 127;
    #pragma unroll
    for (int m=0;m<8;m++){
      const int trow = (bm0&8191) + wr*128 + m*16 + g*4;
      #pragma unroll
      for (int n=0;n<4;n++){
        const int d = dbase + n*16 + ln;
        ushort4 o; u16* op = (u16*)&o;
        #pragma unroll
        for (int r=0;r<4;r++) op[r] = f2b(acc[m][n][r]);
        *(ushort4*)(VT + ((u64)bh*128 + d)*8192 + trow) = o;
      }
    }
  } else {                              // ---- xb1 / xg1
    #pragma unroll
    for (int m=0;m<8;m++)
      #pragma unroll
      for (int n=0;n<4;n++){
        const int col = cw0 + n*16 + ln - 3072;
        #pragma unroll
        for (int r=0;r<4;r++)
          FP[(u64)(bm0 + wr*128 + m*16 + g*4 + r)*384 + col] = f2b(acc[m][n][r]);
      }
  }
}

// ---------------- f / log-decay cumsum: one wave per (bh, chunk) ----------------
__global__ __launch_bounds__(64) void fkernel(const u16* __restrict__ FP,
                                              const float* __restrict__ llb,
                                              float* __restrict__ G, float* __restrict__ GL){
  const int c = blockIdx.x, bh = blockIdx.y;
  const int b = bh>>3, h = bh&7;
  const int t = threadIdx.x;
  const int tok = c*64 + t;
  const float fp = b2f(FP[(u64)(b*8192 + tok)*384 + 256 + h]);
  const float lb = __expf(llb[h]);
  const float f = lb + (1.f - lb) * sigm(fp);
  float x = __logf(f);
  #pragma unroll
  for (int d=1; d<64; d<<=1){
    float v = __shfl_up(x, d);
    if (t >= d) x += v;
  }
  G[(u64)bh*8192 + tok] = x;
  const float gl = __shfl(x, 63);
  if (t == 0) GL[bh*128 + c] = gl;
}

// ---------------- E1: silu(q), beta-normalize, reflect q (in place) ----------------
__global__ __launch_bounds__(256) void e1_reflect(u16* __restrict__ Q,
                                                  const u16* __restrict__ BP){
  const u64 t = blockIdx.x;
  const int tid = threadIdx.x;
  __shared__ float red[8];
  u16* qrow = Q + t*1024;
  const u16* brow = BP + t*1024;
  ushort4 qv = ((const ushort4*)qrow)[tid];
  ushort4 bv = ((const ushort4*)brow)[tid];
  u16* qp = (u16*)&qv; const u16* bp = (const u16*)&bv;
  float q[4], bb[4];
  float s1 = 0.f, s2 = 0.f;
  #pragma unroll
  for (int j=0;j<4;j++){
    const float qq = silu(b2f(qp[j]));
    const float bbv = silu(b2f(bp[j]));
    q[j] = qq; bb[j] = bbv;
    s1 += bbv*bbv; s2 += qq*bbv;
  }
  #pragma unroll
  for (int d=1; d<64; d<<=1){ s1 += __shfl_xor(s1,d); s2 += __shfl_xor(s2,d); }
  const int wid = tid>>6, lane = tid&63;
  if (lane==0){ red[wid]=s1; red[4+wid]=s2; }
  __syncthreads();
  s1 = red[0]+red[1]+red[2]+red[3];
  s2 = red[4]+red[5]+red[6]+red[7];
  const float bs = 1.f/(fmaxf(sqrtf(s1), 1e-6f) * 32.f);
  const float coef = 2.f * s2 * bs * bs;
  #pragma unroll
  for (int j=0;j<4;j++) qp[j] = f2b(q[j] - coef*bb[j]);
  ((ushort4*)qrow)[tid] = qv;
}

// ---------------- G1: chunk-local state S^T[n][d] = sum_i v[i][n]*k'[i][d] ----------------
__global__ __launch_bounds__(256,4) void g1_local(const u16* __restrict__ KT,
                                                  const u16* __restrict__ VT,
                                                  u16* __restrict__ LT){
  __shared__ __align__(16) u16 kts[128*64];
  __shared__ __align__(16) u16 vts[128*64];
  const int c = blockIdx.x, bh = blockIdx.y;
  const int tid = threadIdx.x, lane = tid&63, wid = tid>>6;
  const int g = lane>>4, ln = lane&15;
  #pragma unroll
  for (int j=0;j<4;j++){
    const int p = (wid*4+j)*64 + lane;
    const int row = p>>3, sl = p&7;
    const int sc = ((sl ^ (row&7))<<3);
    gload16(KT + ((u64)bh*128 + row)*8192 + (u64)c*64 + sc, (char*)kts + (wid*4+j)*1024);
    gload16(VT + ((u64)bh*128 + row)*8192 + (u64)c*64 + sc, (char*)vts + (wid*4+j)*1024);
  }
  __syncthreads();
  f32x4 acc[2][8];
  #pragma unroll
  for (int mt=0;mt<2;mt++)
    #pragma unroll
    for (int dt=0;dt<8;dt++) acc[mt][dt] = f32x4{0.f,0.f,0.f,0.f};
  #pragma unroll
  for (int kk=0;kk<2;kk++){
    s16x8 av[2];
    #pragma unroll
    for (int mt=0;mt<2;mt++){
      const int row = wid*32 + mt*16 + ln;
      av[mt] = *(const s16x8*)(vts + row*64 + (((kk*4+g) ^ (row&7))<<3));
    }
    #pragma unroll
    for (int dt=0;dt<8;dt++){
      const int row = dt*16 + ln;
      const s16x8 bk = *(const s16x8*)(kts + row*64 + (((kk*4+g) ^ (row&7))<<3));
      #pragma unroll
      for (int mt=0;mt<2;mt++) acc[mt][dt] = MFMA(av[mt], bk, acc[mt][dt]);
    }
  }
  u16* out = LT + ((u64)(bh*128 + c)<<14);
  #pragma unroll
  for (int mt=0;mt<2;mt++)
    #pragma unroll
    for (int dt=0;dt<8;dt++){
      const int d = dt*16 + ln;
      #pragma unroll
      for (int r=0;r<4;r++){
        const int n = wid*32 + mt*16 + g*4 + r;
        out[n*128 + d] = f2b(acc[mt][dt][r]);
      }
    }
}

// ---------------- G2: in-place chunk scan ----------------
__global__ __launch_bounds__(256) void g2_scan(u16* __restrict__ LS,
                                               const float* __restrict__ GL){
  __shared__ float egl[128];
  const int bh = blockIdx.y;
  if (threadIdx.x < 128) egl[threadIdx.x] = __expf(GL[bh*128 + threadIdx.x]);
  __syncthreads();
  const u64 e = (u64)blockIdx.x*256 + threadIdx.x;
  u16* P = LS + ((u64)bh<<21) + e;
  float s = 0.f;
  for (int c=0;c<128;c++){
    const float l = b2f(P[(u64)c<<14]);
    P[(u64)c<<14] = f2b(s);
    s = egl[c]*s + l;
  }
}

// ---------------- G3: o = decayed-masked(q k^T) @ v + (q e^g) @ S_begin ----------------
__global__ __launch_bounds__(256,2) void g3_out(const u16* __restrict__ Qb,
                                                const u16* __restrict__ Kp,
                                                const u16* __restrict__ VT,
                                                const u16* __restrict__ SBb,
                                                const float* __restrict__ Gb,
                                                u16* __restrict__ O){
  __shared__ __align__(16) u16 qs[64*128];
  __shared__ __align__(16) u16 ks[64*128];
  __shared__ __align__(16) u16 vts[128*64];
  __shared__ __align__(16) u16 sbs[64*128];
  __shared__ __align__(16) u16 Ast[4][16*64];
  __shared__ float gg[64];
  const int c = blockIdx.x, bh = blockIdx.y;
  const int b = bh>>3, h = bh&7;
  const int tid = threadIdx.x, lane = tid&63, wid = tid>>6;
  const int g = lane>>4, ln = lane&15;
  const u64 trow0 = (u64)b*8192 + (u64)c*64;

  if (tid < 64) gg[tid] = Gb[(u64)bh*8192 + c*64 + tid];

  const u16* sbbase = SBb + ((u64)(bh*128 + c)<<14);
  #pragma unroll
  for (int j=0;j<4;j++){
    const int p = (wid*4+j)*64 + lane;
    const int row = p>>4, sl = p&15;
    const int sc = ((sl ^ (row&7))<<3);
    gload16(Qb + (trow0 + row)*1024 + h*128 + sc, (char*)qs + (wid*4+j)*1024);
    gload16(Kp + (trow0 + row)*1024 + h*128 + sc, (char*)ks + (wid*4+j)*1024);
    const int row2 = p>>3, sl2 = p&7;
    gload16(VT + ((u64)bh*128 + row2)*8192 + (u64)c*64 + ((sl2 ^ (row2&7))<<3),
            (char*)vts + (wid*4+j)*1024);
    gload16(sbbase + row*128 + sc, (char*)sbs + (wid*4+j)*1024);
  }
  __syncthreads();

  f32x4 pa[4];
  #pragma unroll
  for (int jt=0;jt<4;jt++) pa[jt] = f32x4{0.f,0.f,0.f,0.f};
  #pragma unroll
  for (int kk=0;kk<4;kk++){
    const int arow = wid*16 + ln;
    const s16x8 aq = *(const s16x8*)(qs + arow*128 + (((kk*4+g) ^ (arow&7))<<3));
    #pragma unroll
    for (int jt=0;jt<4;jt++){
      const int brow = jt*16 + ln;
      const s16x8 bk = *(const s16x8*)(ks + brow*128 + (((kk*4+g) ^ (brow&7))<<3));
      pa[jt] = MFMA(aq, bk, pa[jt]);
    }
  }
  #pragma unroll
  for (int jt=0;jt<4;jt++){
    const int jj = jt*16 + ln;
    const float gj = gg[jj];
    #pragma unroll
    for (int r=0;r<4;r++){
      const int il = g*4 + r;
      const int ii = wid*16 + il;
      const float v = (jj <= ii) ? pa[jt][r] * __expf(gg[ii] - gj) : 0.f;
      Ast[wid][il*64 + (((jj>>3) ^ (il&7))<<3) + (jj&7)] = f2b(v);
    }
  }
  {
    const int row = wid*16 + (lane>>2);
    const float sc = __expf(gg[row]);
    u16* base = qs + row*128 + (lane&3)*32;
    #pragma unroll
    for (int ee=0; ee<4; ee++){
      s16x8 v = *(s16x8*)(base + ee*8);
      u16* vp = (u16*)&v;
      #pragma unroll
      for (int xj=0;xj<8;xj++) vp[xj] = f2b(b2f(vp[xj]) * sc);
      *(s16x8*)(base + ee*8) = v;
    }
  }
  f32x4 acc[8];
  #pragma unroll
  for (int i=0;i<8;i++) acc[i] = f32x4{0.f,0.f,0.f,0.f};
  #pragma unroll
  for (int kk=0;kk<2;kk++){
    const s16x8 aa = *(const s16x8*)(Ast[wid] + ln*64 + (((kk*4+g) ^ (ln&7))<<3));
    #pragma unroll
    for (int nt=0;nt<8;nt++){
      const int brow = nt*16 + ln;
      const s16x8 bb = *(const s16x8*)(vts + brow*64 + (((kk*4+g) ^ (brow&7))<<3));
      acc[nt] = MFMA(aa, bb, acc[nt]);
    }
  }
  #pragma unroll
  for (int kk=0;kk<4;kk++){
    const int arow = wid*16 + ln;
    const s16x8 aq = *(const s16x8*)(qs + arow*128 + (((kk*4+g) ^ (arow&7))<<3));
    #pragma unroll
    for (int nt=0;nt<4;nt++){
      const int brow = nt*16 + ln;
      const s16x8 bs = *(const s16x8*)(sbs + brow*128 + (((kk*4+g) ^ (brow&7))<<3));
      acc[nt] = MFMA(aq, bs, acc[nt]);
    }
  }
  __syncthreads();
  #pragma unroll
  for (int j=0;j<4;j++){
    const int p = (wid*4+j)*64 + lane;
    const int row = p>>4, sl = p&15;
    gload16(sbbase + 8192 + row*128 + ((sl ^ (row&7))<<3), (char*)sbs + (wid*4+j)*1024);
  }
  __syncthreads();
  #pragma unroll
  for (int kk=0;kk<4;kk++){
    const int arow = wid*16 + ln;
    const s16x8 aq = *(const s16x8*)(qs + arow*128 + (((kk*4+g) ^ (arow&7))<<3));
    #pragma unroll
    for (int nt=0;nt<4;nt++){
      const int brow = nt*16 + ln;
      const s16x8 bs = *(const s16x8*)(sbs + brow*128 + (((kk*4+g) ^ (brow&7))<<3));
      acc[4+nt] = MFMA(aq, bs, acc[4+nt]);
    }
  }
  u16* outp = O + trow0*1024 + h*128;
  #pragma unroll
  for (int nt=0;nt<8;nt++){
    const int n = nt*16 + ln;
    #pragma unroll
    for (int r=0;r<4;r++){
      const int i = wid*16 + g*4 + r;
      outp[(u64)i*1024 + n] = f2b(acc[nt][r]);
    }
  }
}

// ---------------- E2: gate + LayerNorm -> bf16 ----------------
__global__ __launch_bounds__(256) void e2_ln(const u16* __restrict__ O,
                                             const u16* __restrict__ GP,
                                             const float* __restrict__ lnsc,
                                             const float* __restrict__ lnbi,
                                             u16* __restrict__ OL){
  const u64 t = blockIdx.x;
  const int tid = threadIdx.x;
  __shared__ float red[8];
  ushort4 ov = ((const ushort4*)(O + t*1024))[tid];
  ushort4 gv = ((const ushort4*)(GP + t*1024))[tid];
  const u16* ovp = (const u16*)&ov;
  const u16* gvp = (const u16*)&gv;
  float o[4]; float s = 0.f, s2 = 0.f;
  #pragma unroll
  for (int j=0;j<4;j++){
    const float val = b2f(ovp[j]) * sigm(b2f(gvp[j]));
    o[j] = val; s += val; s2 += val*val;
  }
  #pragma unroll
  for (int d=1; d<64; d<<=1){ s += __shfl_xor(s,d); s2 += __shfl_xor(s2,d); }
  const int wid = tid>>6, lane = tid&63;
  if (lane==0){ red[wid]=s; red[4+wid]=s2; }
  __syncthreads();
  s = red[0]+red[1]+red[2]+red[3];
  s2 = red[4]+red[5]+red[6]+red[7];
  const float mu = s * (1.f/1024.f);
  const float var = s2 * (1.f/1024.f) - mu*mu;
  const float rs = rsqrtf(var + 1e-5f);
  ushort4 out; u16* op = (u16*)&out;
  #pragma unroll
  for (int j=0;j<4;j++){
    const int e = tid*4 + j;
    op[j] = f2b((o[j]-mu)*rs*lnsc[e] + lnbi[e]);
  }
  ((ushort4*)(OL + t*1024))[tid] = out;
}

extern "C" void kernel_launch(void* const* d_in, const int* in_sizes, int n_in,
                              void* d_out, int out_size, void* d_ws, size_t ws_size,
                              hipStream_t stream){
  const float* x   = (const float*)d_in[0];
  const float* llb = (const float*)d_in[1];
  const float* Wq  = (const float*)d_in[2];
  const float* Wk  = (const float*)d_in[3];
  const float* Wv  = (const float*)d_in[4];
  const float* Wf  = (const float*)d_in[5];
  const float* Wb1 = (const float*)d_in[6];
  const float* Wb2 = (const float*)d_in[7];
  const float* Wg1 = (const float*)d_in[8];
  const float* Wg2 = (const float*)d_in[9];
  const float* Wo  = (const float*)d_in[10];
  const float* lnsc= (const float*)d_in[11];
  const float* lnbi= (const float*)d_in[12];

  const u64 REQUIRED = 190586880ull;
  if (ws_size < REQUIRED){
    const float val = 1.0e6f + (float)(u64)(ws_size>>20) * 1024.0f;
    fill_diag<<<dim3((out_size+255)/256),256,0,stream>>>((float*)d_out, out_size, val);
    return;
  }

  char* ws = (char*)d_ws;
  u16*  WCAT = (u16*)(ws + 0ull);
  u16*  WB2T = (u16*)(ws + 7077888ull);
  u16*  WG2T = (u16*)(ws + 7340032ull);
  u16*  WOT  = (u16*)(ws + 7602176ull);
  float* Gb  = (float*)(ws + 9699328ull);
  float* GLb = (float*)(ws + 10223616ull);
  u16*  FP   = (u16*)(ws + 10231808ull);
  u16*  R0   = (u16*)(ws + 22814720ull);   // XB -> BP -> GP
  u16*  Qb   = (u16*)(ws + 56369152ull);   // -> OL
  u16*  Kp   = (u16*)(ws + 89923584ull);
  u16*  KT   = (u16*)(ws + 123478016ull);  // -> Ob
  u16*  VT   = (u16*)(ws + 157032448ull);
  u16*  LTSB = (u16*)d_out;                // dead before final GEMM
  u16*  XB = R0, *BP = R0, *GP = R0;
  u16*  Ob = KT, *OL = Qb;

  cast_bf<<<dim3(4096),256,0,stream>>>((const float4*)x, (ushort4*)XB, 16384*1024/4);
  wprep_all<<<dim3(16,16,9),256,0,stream>>>(Wq,Wk,Wv,Wf,Wb1,Wb2,Wg1,Wg2,Wo,
                                            WCAT, WB2T, WG2T, WOT);

  // fpre (small N=128) on the 128² kernel, then decay cumsum
  gemm_bt<<<dim3(1,128),256,0,stream>>>(XB, 1024, WCAT + 3328*1024, FP + 256, 384, 1024, 1);
  fkernel<<<dim3(128,16),64,0,stream>>>(FP, llb, Gb, GLb);

  // merged q|k|v|xb1|xg1 projection (256² pipelined)
  gemm_proj<<<dim3(13,64),512,0,stream>>>(XB, WCAT, Qb, Kp, KT, VT, FP, Gb, GLb);

  // XB dead -> BP into R0
  gemm256<<<dim3(4,64),512,0,stream>>>(FP, 384, WB2T, BP, 1024, 128, 1);
  e1_reflect<<<dim3(16384),256,0,stream>>>(Qb, BP);

  // BP dead -> GP into R0
  gemm256<<<dim3(4,64),512,0,stream>>>(FP + 128, 384, WG2T, GP, 1024, 128, 1);

  g1_local<<<dim3(128,16),256,0,stream>>>(KT, VT, LTSB);
  g2_scan<<<dim3(64,16),256,0,stream>>>(LTSB, GLb);
  g3_out<<<dim3(128,16),256,0,stream>>>(Qb, Kp, VT, LTSB, Gb, Ob);   // Ob in dead KT

  e2_ln<<<dim3(16384),256,0,stream>>>(Ob, GP, lnsc, lnbi, OL);       // OL in dead Qb

  gemm256<<<dim3(4,64),512,0,stream>>>(OL, 1024, WOT, d_out, 1024, 1024, 0);
}